// Round 3
// baseline (654.794 us; speedup 1.0000x reference)
//
#include <hip/hip_runtime.h>
#include <math.h>

#define NTOK 3136           // 16*14*14 tokens
#define MT 12544            // 4 * NTOK
#define KCV 2304            // 3*3*16*16
#define THRESH 1.5f
#define LN_EPS 1e-5f

typedef short short8 __attribute__((ext_vector_type(8)));
typedef float f32x4 __attribute__((ext_vector_type(4)));

// ---------- bf16 helpers (RTNE) ----------
__device__ __forceinline__ unsigned short f2bf(float f) {
    unsigned int u = __float_as_uint(f);
    u += 0x7fffu + ((u >> 16) & 1u);
    return (unsigned short)(u >> 16);
}
__device__ __forceinline__ float bf2f(unsigned short h) {
    return __uint_as_float(((unsigned int)h) << 16);
}
__device__ __forceinline__ void async16(const void* g, void* l) {
    __builtin_amdgcn_global_load_lds((const __attribute__((address_space(1))) void*)g,
                                     (__attribute__((address_space(3))) void*)l, 16, 0, 0);
}

// ---------- wave helpers (wave = 64) ----------
__device__ __forceinline__ float wsum(float v) {
#pragma unroll
    for (int o = 32; o > 0; o >>= 1) v += __shfl_xor(v, o);
    return v;
}
__device__ __forceinline__ float wmax(float v) {
#pragma unroll
    for (int o = 32; o > 0; o >>= 1) v = fmaxf(v, __shfl_xor(v, o));
    return v;
}

// ---------- weight prep (merged): conv_w -> hi/lo bf16 ; 6 matrices -> bf16 pool ----------
__global__ __launch_bounds__(256) void prep_k(
    const float* __restrict__ cw, unsigned short* __restrict__ cwh, unsigned short* __restrict__ cwl,
    const float* __restrict__ s0, const float* __restrict__ s1, const float* __restrict__ s2,
    const float* __restrict__ s3, const float* __restrict__ s4, const float* __restrict__ s5,
    unsigned short* __restrict__ dst)
{
    int i = blockIdx.x * 256 + threadIdx.x;
    if (i < 589824) {                      // 256*KCV
        float a = cw[i];
        unsigned short h = f2bf(a);
        cwh[i] = h;
        cwl[i] = f2bf(a - bf2f(h));
        return;
    }
    int j = i - 589824;
    if (j >= 524288) return;
    float v;
    if      (j <  65536) v = s0[j];
    else if (j < 131072) v = s1[j - 65536];
    else if (j < 327680) v = s2[j - 131072];
    else if (j < 393216) v = s3[j - 327680];
    else if (j < 458752) v = s4[j - 393216];
    else                 v = s5[j - 458752];
    dst[j] = f2bf(v);
}

// ---------- conv implicit GEMM, barrier-free: A and B fragments straight to registers ----------
// out[m,e] = relu(sum_k A[m,k]*cw[e,k] + cb[e]);  A*B ~ Ah*Bh + Ah*Bl + Al*Bh
// A-frag (16x16x32): lane = (lq=l>>4, l15=l&15): row m0+w*16+l15, k = lq*8+j  -> 8 contiguous floats
__global__ __launch_bounds__(256) void conv_direct_k(
    const float* __restrict__ video, const unsigned short* __restrict__ cwh,
    const unsigned short* __restrict__ cwl, const float* __restrict__ cb,
    float* __restrict__ outF, unsigned short* __restrict__ outB)
{
    const int t    = threadIdx.x;
    const int lane = t & 63;
    const int w    = t >> 6;
    const int m0   = blockIdx.x * 64;
    const int e0   = blockIdx.y * 64;
    const int l15  = lane & 15, lq = lane >> 4;

    // row geometry (per lane): m = b*3136 + d*196 + h*14 + w'
    int m = m0 + w * 16 + l15;
    int b = m / NTOK, n = m % NTOK;
    int d = n / 196, hw = n % 196;
    int h = hw / 14, ww = hw % 14;
    const float* vb = video + (size_t)(b * 3) * 1605632 + (h * 16) * 224 + ww * 16
                    + (lq >> 1) * 224 + (lq & 1) * 8;   // + kh(lq)*224 + kw(lq)
    int dbase = 2 * d - 1;
    const unsigned short* bh0 = cwh + (size_t)(e0 + l15) * KCV + lq * 8;
    const unsigned short* bl0 = cwl + (size_t)(e0 + l15) * KCV + lq * 8;

    f32x4 acc[4] = {};
    for (int c = 0; c < 3; ++c) {
        const float* vc = vb + (size_t)c * 1605632;
        for (int kd = 0; kd < 3; ++kd) {
            int id = dbase + kd;
            const float* vd = vc + id * 50176;
            bool ok = (id >= 0);
            int kbase = c * 768 + kd * 256;
#pragma unroll
            for (int kp = 0; kp < 8; ++kp) {
                float4 a0 = make_float4(0.f, 0.f, 0.f, 0.f), a1 = a0;
                if (ok) {
                    const float* p = vd + kp * 448;     // 2 kh rows per 32-k step
                    a0 = *(const float4*)p;
                    a1 = *(const float4*)(p + 4);
                }
                short8 fah, fal;
                float av[8] = {a0.x, a0.y, a0.z, a0.w, a1.x, a1.y, a1.z, a1.w};
#pragma unroll
                for (int j = 0; j < 8; ++j) {
                    unsigned short hi = f2bf(av[j]);
                    fah[j] = (short)hi;
                    fal[j] = (short)f2bf(av[j] - bf2f(hi));
                }
                int ko = kbase + kp * 32;
#pragma unroll
                for (int ct = 0; ct < 4; ++ct) {
                    short8 fbh = *(const short8*)(bh0 + (size_t)ct * 16 * KCV + ko);
                    short8 fbl = *(const short8*)(bl0 + (size_t)ct * 16 * KCV + ko);
                    acc[ct] = __builtin_amdgcn_mfma_f32_16x16x32_bf16(fah, fbh, acc[ct], 0, 0, 0);
                    acc[ct] = __builtin_amdgcn_mfma_f32_16x16x32_bf16(fah, fbl, acc[ct], 0, 0, 0);
                    acc[ct] = __builtin_amdgcn_mfma_f32_16x16x32_bf16(fal, fbh, acc[ct], 0, 0, 0);
                }
            }
        }
    }
    // C/D: col = lane&15, row = (lane>>4)*4 + reg
    int rbase = m0 + w * 16 + lq * 4;
#pragma unroll
    for (int ct = 0; ct < 4; ++ct) {
        int e = e0 + ct * 16 + l15;
        float bias = cb[e];
#pragma unroll
        for (int r = 0; r < 4; ++r) {
            float v = fmaxf(acc[ct][r] + bias, 0.f);
            size_t off = (size_t)(rbase + r) * 256 + e;
            outF[off] = v;
            outB[off] = f2bf(v);
        }
    }
}

// ---------- bf16 MFMA GEMM, K=256 staged fully in LDS (one barrier) ----------
// C[m,e] = sum_k A[m,k]*W[e,k] + bias[e] (+addvec[e]) (mask m%NTOK >= *Sptr -> 0)
// optional fused score epilogue: scOut[(b*4+blockIdx.y)*NTOK+n] = sum_e C[m,e]*qpv[e]
__global__ __launch_bounds__(256) void gemm_mfma_k(
    const unsigned short* __restrict__ A, const unsigned short* __restrict__ W,
    const float* __restrict__ bias, const float* __restrict__ addvec,
    const int* __restrict__ Sptr, float* __restrict__ outF, unsigned short* __restrict__ outB,
    const float* __restrict__ qpv, float* __restrict__ scOut)
{
    __shared__ __align__(16) unsigned short As[16384], Bs[16384];   // 32 KB + 32 KB
    const int t = threadIdx.x, lane = t & 63, w = t >> 6;
    const int m0 = blockIdx.x * 64, e0 = blockIdx.y * 64;
    const int l15 = lane & 15, lq = lane >> 4;
    const unsigned short* ga = A + (size_t)(m0 + lane) * 256;
    const unsigned short* gb = W + (size_t)(e0 + lane) * 256;
#pragma unroll
    for (int kg = w; kg < 32; kg += 4) {
        async16(ga + kg * 8, &As[kg * 512]);
        async16(gb + kg * 8, &Bs[kg * 512]);
    }
    f32x4 acc[4] = {};
    __syncthreads();
#pragma unroll
    for (int s = 0; s < 8; ++s) {
        int kg = s * 4 + lq;
        short8 a = *(const short8*)&As[(kg * 64 + w * 16 + l15) * 8];
#pragma unroll
        for (int ct = 0; ct < 4; ++ct) {
            short8 bb = *(const short8*)&Bs[(kg * 64 + ct * 16 + l15) * 8];
            acc[ct] = __builtin_amdgcn_mfma_f32_16x16x32_bf16(a, bb, acc[ct], 0, 0, 0);
        }
    }
    int S = Sptr ? *Sptr : 0x7fffffff;
    int rbase = m0 + w * 16 + lq * 4;
    float p[4] = {0.f, 0.f, 0.f, 0.f};
#pragma unroll
    for (int ct = 0; ct < 4; ++ct) {
        int e = e0 + ct * 16 + l15;
        float bv = bias[e] + (addvec ? addvec[e] : 0.f);
        float qv = qpv ? qpv[e] : 0.f;
#pragma unroll
        for (int r = 0; r < 4; ++r) {
            int mm = rbase + r;
            float v = acc[ct][r] + bv;
            if ((mm % NTOK) >= S) v = 0.f;
            size_t off = (size_t)mm * 256 + e;
            if (outF) outF[off] = v;
            if (outB) outB[off] = f2bf(v);
            p[r] += v * qv;
        }
    }
    if (scOut) {
#pragma unroll
        for (int r = 0; r < 4; ++r) {
            p[r] += __shfl_xor(p[r], 1); p[r] += __shfl_xor(p[r], 2);
            p[r] += __shfl_xor(p[r], 4); p[r] += __shfl_xor(p[r], 8);
        }
        if (l15 == 0) {
#pragma unroll
            for (int r = 0; r < 4; ++r) {
                int mm = rbase + r;
                int b = mm / NTOK, n = mm % NTOK;
                scOut[(b * 4 + blockIdx.y) * NTOK + n] = p[r];
            }
        }
    }
}

// ---------- byte -> entropy -> boundary (b=0 only); one wave per token ----------
__global__ __launch_bounds__(256) void boundary_k(
    const float* __restrict__ tokens, const float* __restrict__ ent_table,
    int* __restrict__ boundary)
{
    int n    = blockIdx.x * 4 + (threadIdx.x >> 6);
    int lane = threadIdx.x & 63;
    const float4 x = reinterpret_cast<const float4*>(tokens + (size_t)n * 256)[lane];
    float mean = wsum(x.x + x.y + x.z + x.w) * (1.f / 256.f);
    float bf = rintf(mean * 255.f);
    bf = fminf(fmaxf(bf, 0.f), 255.f);
    int byte = (int)bf;
    const float4 lg = reinterpret_cast<const float4*>(ent_table + byte * 256)[lane];
    float mx = wmax(fmaxf(fmaxf(lg.x, lg.y), fmaxf(lg.z, lg.w)));
    float e0 = expf(lg.x - mx), e1 = expf(lg.y - mx), e2 = expf(lg.z - mx), e3 = expf(lg.w - mx);
    float z = wsum(e0 + e1 + e2 + e3);
    float iz = 1.f / z;
    float p0 = e0 * iz, p1 = e1 * iz, p2 = e2 * iz, p3 = e3 * iz;
    float ep = -(p0 * log2f(p0 + 1e-9f) + p1 * log2f(p1 + 1e-9f) +
                 p2 * log2f(p2 + 1e-9f) + p3 * log2f(p3 + 1e-9f));
    ep = wsum(ep);
    if (lane == 0) boundary[n] = (ep > THRESH) ? 1 : 0;
}

// ---------- single-block scan: boundary -> seg_start[], S ----------
__global__ __launch_bounds__(256) void scan_k(const int* __restrict__ boundary,
    int* __restrict__ seg_start, int* __restrict__ Sptr)
{
    __shared__ int sums[256];
    const int t = threadIdx.x;
    const int CH = 13;
    int base = t * CH;
    int s = 0;
    for (int i = 0; i < CH; i++) { int n = base + i; if (n < NTOK) s += boundary[n]; }
    sums[t] = s; __syncthreads();
    for (int o = 1; o < 256; o <<= 1) {
        int v = sums[t];
        int u = (t >= o) ? sums[t - o] : 0;
        __syncthreads();
        sums[t] = v + u;
        __syncthreads();
    }
    int run = (t == 0) ? 0 : sums[t - 1];
    if (t == 0) seg_start[0] = 0;
    for (int i = 0; i < CH; i++) {
        int n = base + i;
        if (n >= NTOK) break;
        int v = boundary[n];
        if (n == NTOK - 1) { Sptr[0] = run + 1; seg_start[run + 1] = NTOK; }
        if (v && (n + 1 < NTOK)) seg_start[run + 1] = n + 1;
        run += v;
    }
}

// ---------- row LayerNorm: fp32 in -> bf16 out; one wave per row ----------
__global__ __launch_bounds__(256) void ln_bf_k(const float* __restrict__ X,
    const float* __restrict__ g, const float* __restrict__ b, unsigned short* __restrict__ Y)
{
    int row  = blockIdx.x * 4 + (threadIdx.x >> 6);
    int lane = threadIdx.x & 63;
    float4 x = reinterpret_cast<const float4*>(X + (size_t)row * 256)[lane];
    float m = wsum(x.x + x.y + x.z + x.w) * (1.f / 256.f);
    float d0 = x.x - m, d1 = x.y - m, d2 = x.z - m, d3 = x.w - m;
    float var = wsum(d0 * d0 + d1 * d1 + d2 * d2 + d3 * d3) * (1.f / 256.f);
    float inv = 1.f / sqrtf(var + LN_EPS);
    float4 g4 = reinterpret_cast<const float4*>(g)[lane];
    float4 b4 = reinterpret_cast<const float4*>(b)[lane];
    ushort4 y;
    y.x = f2bf(d0 * inv * g4.x + b4.x);
    y.y = f2bf(d1 * inv * g4.y + b4.y);
    y.z = f2bf(d2 * inv * g4.z + b4.z);
    y.w = f2bf(d3 * inv * g4.w + b4.w);
    reinterpret_cast<ushort4*>(Y + (size_t)row * 256)[lane] = y;
}

// ---------- query path: qp[256], batch-invariant, one block, coalesced ----------
__global__ __launch_bounds__(256) void query_k(
    const float* __restrict__ gq, const float* __restrict__ wq_w, const float* __restrict__ wq_b,
    const float* __restrict__ lnq_g, const float* __restrict__ lnq_b,
    const float* __restrict__ inW, const float* __restrict__ inB, float* __restrict__ qp)
{
    __shared__ __align__(16) float sh[256];
    __shared__ float red[256];
    const int t = threadIdx.x, w = t >> 6, lane = t & 63;
    float4 g4 = reinterpret_cast<const float4*>(gq)[lane];
    for (int i = 0; i < 64; ++i) {
        int o = w * 64 + i;
        float4 wr = reinterpret_cast<const float4*>(wq_w + (size_t)o * 256)[lane];
        float pv = wsum(g4.x * wr.x + g4.y * wr.y + g4.z * wr.z + g4.w * wr.w);
        if (lane == 0) sh[o] = pv + wq_b[o];
    }
    __syncthreads();
    float acc = sh[t];
    red[t] = acc; __syncthreads();
    for (int o = 128; o > 0; o >>= 1) { if (t < o) red[t] += red[t + o]; __syncthreads(); }
    float m = red[0] * (1.f / 256.f);
    __syncthreads();
    float d = acc - m;
    red[t] = d * d; __syncthreads();
    for (int o = 128; o > 0; o >>= 1) { if (t < o) red[t] += red[t + o]; __syncthreads(); }
    float inv = 1.f / sqrtf(red[0] * (1.f / 256.f) + LN_EPS);
    __syncthreads();
    sh[t] = d * inv * lnq_g[t] + lnq_b[t];
    __syncthreads();
    float4 s4 = reinterpret_cast<const float4*>(sh)[lane];
    for (int i = 0; i < 64; ++i) {
        int o = w * 64 + i;
        float4 wr = reinterpret_cast<const float4*>(inW + (size_t)o * 256)[lane];
        float pv = wsum(s4.x * wr.x + s4.y * wr.y + s4.z * wr.z + s4.w * wr.w);
        if (lane == 0) qp[o] = (pv + inB[o]) * 0.125f;
    }
}

// ---------- segment softmax-attention; grid (NTOK, NH); wave = batch ----------
__global__ __launch_bounds__(256) void attn_bf_k(const float* __restrict__ sc,
    const unsigned short* __restrict__ vp, const int* __restrict__ seg_start,
    const int* __restrict__ Sptr, unsigned short* __restrict__ attn)
{
    int s    = blockIdx.x;
    int h    = blockIdx.y;
    int b    = threadIdx.x >> 6;
    int lane = threadIdx.x & 63;
    unsigned short* orow = attn + ((size_t)b * NTOK + s) * 256 + h * 64;
    int S = *Sptr;
    if (s >= S) { orow[lane] = 0; return; }
    int st = seg_start[s], en = seg_start[s + 1];
    const float* scr = sc + (b * 4 + h) * NTOK;
    float m = -1e30f;
    for (int n = st; n < en; n++) m = fmaxf(m, scr[n]);
    float den = 0.f, acc = 0.f;
    for (int n = st; n < en; n++) {
        float wgt = expf(scr[n] - m);
        den += wgt;
        acc += wgt * bf2f(vp[((size_t)b * NTOK + n) * 256 + h * 64 + lane]);
    }
    orow[lane] = f2bf(acc / den);
}

extern "C" void kernel_launch(void* const* d_in, const int* in_sizes, int n_in,
                              void* d_out, int out_size, void* d_ws, size_t ws_size,
                              hipStream_t stream)
{
    const float* video      = (const float*)d_in[0];
    const float* conv_w     = (const float*)d_in[1];
    const float* conv_b     = (const float*)d_in[2];
    const float* wq_w       = (const float*)d_in[3];
    const float* wq_b       = (const float*)d_in[4];
    const float* wk_w       = (const float*)d_in[5];
    const float* wk_b       = (const float*)d_in[6];
    const float* wv_w       = (const float*)d_in[7];
    const float* wv_b       = (const float*)d_in[8];
    const float* lnq_g      = (const float*)d_in[9];
    const float* lnq_b      = (const float*)d_in[10];
    const float* lnk_g      = (const float*)d_in[11];
    const float* lnk_b      = (const float*)d_in[12];
    const float* lnv_g      = (const float*)d_in[13];
    const float* lnv_b      = (const float*)d_in[14];
    const float* in_proj_w  = (const float*)d_in[15];
    const float* in_proj_b  = (const float*)d_in[16];
    const float* out_proj_w = (const float*)d_in[17];
    const float* out_proj_b = (const float*)d_in[18];
    const float* dense_w    = (const float*)d_in[19];
    const float* dense_b    = (const float*)d_in[20];
    const float* bproj_w    = (const float*)d_in[21];
    const float* bproj_b    = (const float*)d_in[22];
    const float* group_q    = (const float*)d_in[23];
    const float* ent_table  = (const float*)d_in[24];
    float* out = (float*)d_out;

    // ---- workspace layout ----
    float* W1f = (float*)d_ws;                         // fp32 tokens (for byte path)
    float* P   = W1f + (size_t)MT * 256;               // fp32 pre-LN buffer
    unsigned short* B1 = (unsigned short*)(P + (size_t)MT * 256);  // tokens_b16 / attn_b16
    unsigned short* B2 = B1 + (size_t)MT * 256;        // kln/vln/o1
    unsigned short* B3 = B2 + (size_t)MT * 256;        // vp/o2
    unsigned short* cwh = B3 + (size_t)MT * 256;       // conv weights hi
    unsigned short* cwl = cwh + 256 * KCV;             // conv weights lo
    unsigned short* wpool = cwl + 256 * KCV;           // 524288 bf16 weights
    float* sc = (float*)(wpool + 524288);              // scores [B*NH][NTOK]
    float* qp = sc + 16 * NTOK;
    int* boundary  = (int*)(qp + 256);
    int* seg_start = boundary + NTOK;
    int* Sp        = seg_start + (NTOK + 1);

    const unsigned short* wkb    = wpool;
    const unsigned short* wvb    = wpool + 65536;
    const unsigned short* inpb   = wpool + 131072;     // 3E x E
    const unsigned short* outpb  = wpool + 327680;
    const unsigned short* denseb = wpool + 393216;
    const unsigned short* bprojb = wpool + 458752;

    dim3 gG(196, 4), blk(256);
    prep_k<<<dim3(4352), blk, 0, stream>>>(conv_w, cwh, cwl, wk_w, wv_w, in_proj_w,
                                           out_proj_w, dense_w, bproj_w, wpool);
    conv_direct_k<<<gG, blk, 0, stream>>>(video, cwh, cwl, conv_b, W1f, B1);
    boundary_k<<<dim3(NTOK / 4), blk, 0, stream>>>(W1f, ent_table, boundary);
    scan_k<<<dim3(1), blk, 0, stream>>>(boundary, seg_start, Sp);
    query_k<<<dim3(1), blk, 0, stream>>>(group_q, wq_w, wq_b, lnq_g, lnq_b,
                                         in_proj_w, in_proj_b, qp);
    // K path (scores fused into kp GEMM epilogue; kp itself never materialized)
    gemm_mfma_k<<<gG, blk, 0, stream>>>(B1, wkb, wk_b, nullptr, nullptr, P, nullptr,
                                        nullptr, nullptr);
    ln_bf_k<<<dim3(MT / 4), blk, 0, stream>>>(P, lnk_g, lnk_b, B2);
    gemm_mfma_k<<<gG, blk, 0, stream>>>(B2, inpb + 65536, in_proj_b + 256,
                                        nullptr, nullptr, nullptr, nullptr, qp, sc);
    // V path
    gemm_mfma_k<<<gG, blk, 0, stream>>>(B1, wvb, wv_b, nullptr, nullptr, P, nullptr,
                                        nullptr, nullptr);
    ln_bf_k<<<dim3(MT / 4), blk, 0, stream>>>(P, lnv_g, lnv_b, B2);
    gemm_mfma_k<<<gG, blk, 0, stream>>>(B2, inpb + 131072, in_proj_b + 512,
                                        nullptr, nullptr, nullptr, B3, nullptr, nullptr);
    // segment attention
    attn_bf_k<<<dim3(NTOK, 4), blk, 0, stream>>>(sc, B3, seg_start, Sp, B1);
    // tail projections
    gemm_mfma_k<<<gG, blk, 0, stream>>>(B1, outpb, out_proj_b, nullptr, nullptr,
                                        nullptr, B2, nullptr, nullptr);
    gemm_mfma_k<<<gG, blk, 0, stream>>>(B2, denseb, dense_b, group_q, nullptr,
                                        nullptr, B3, nullptr, nullptr);
    gemm_mfma_k<<<gG, blk, 0, stream>>>(B3, bprojb, bproj_b, nullptr, Sp,
                                        out, nullptr, nullptr, nullptr);
}

// Round 4
// 464.363 us; speedup vs baseline: 1.4101x; 1.4101x over previous
//
#include <hip/hip_runtime.h>
#include <math.h>

#define NTOK 3136           // 16*14*14 tokens
#define MT 12544            // 4 * NTOK
#define KCV 2304            // 3*3*16*16
#define THRESH 1.5f
#define LN_EPS 1e-5f

typedef short short8 __attribute__((ext_vector_type(8)));
typedef float f32x4 __attribute__((ext_vector_type(4)));

// ---------- bf16 helpers (RTNE) ----------
__device__ __forceinline__ unsigned short f2bf(float f) {
    unsigned int u = __float_as_uint(f);
    u += 0x7fffu + ((u >> 16) & 1u);
    return (unsigned short)(u >> 16);
}
__device__ __forceinline__ float bf2f(unsigned short h) {
    return __uint_as_float(((unsigned int)h) << 16);
}
__device__ __forceinline__ void async16(const void* g, void* l) {
    __builtin_amdgcn_global_load_lds((const __attribute__((address_space(1))) void*)g,
                                     (__attribute__((address_space(3))) void*)l, 16, 0, 0);
}

// ---------- wave helpers (wave = 64) ----------
__device__ __forceinline__ float wsum(float v) {
#pragma unroll
    for (int o = 32; o > 0; o >>= 1) v += __shfl_xor(v, o);
    return v;
}
__device__ __forceinline__ float wmax(float v) {
#pragma unroll
    for (int o = 32; o > 0; o >>= 1) v = fmaxf(v, __shfl_xor(v, o));
    return v;
}

// ---------- weight prep (merged): conv_w -> hi/lo bf16 ; 6 matrices -> bf16 pool ----------
__global__ __launch_bounds__(256) void prep_k(
    const float* __restrict__ cw, unsigned short* __restrict__ cwh, unsigned short* __restrict__ cwl,
    const float* __restrict__ s0, const float* __restrict__ s1, const float* __restrict__ s2,
    const float* __restrict__ s3, const float* __restrict__ s4, const float* __restrict__ s5,
    unsigned short* __restrict__ dst)
{
    int i = blockIdx.x * 256 + threadIdx.x;
    if (i < 589824) {                      // 256*KCV
        float a = cw[i];
        unsigned short h = f2bf(a);
        cwh[i] = h;
        cwl[i] = f2bf(a - bf2f(h));
        return;
    }
    int j = i - 589824;
    if (j >= 524288) return;
    float v;
    if      (j <  65536) v = s0[j];
    else if (j < 131072) v = s1[j - 65536];
    else if (j < 327680) v = s2[j - 131072];
    else if (j < 393216) v = s3[j - 327680];
    else if (j < 458752) v = s4[j - 393216];
    else                 v = s5[j - 458752];
    dst[j] = f2bf(v);
}

// ---------- conv implicit GEMM on MFMA (round-2 LDS structure) ----------
// out[m,e] = relu(sum_k A[m,k]*cw[e,k] + cb[e])
// batch 0 (blockIdx.x<49): hi/lo split, Ah*Bh + Ah*Bl + Al*Bh (fp32-accurate byte path)
// batches 1-3: plain bf16, 1 MFMA (continuous path, bf16-tolerant)
__global__ __launch_bounds__(256) void conv_mfma2_k(
    const float* __restrict__ video, const unsigned short* __restrict__ cwh,
    const unsigned short* __restrict__ cwl, const float* __restrict__ cb,
    float* __restrict__ outF, unsigned short* __restrict__ outB)
{
    __shared__ __align__(16) unsigned short Ah[2048], Al[2048], Bh[2048], Bl[2048];
    const int t    = threadIdx.x;
    const int lane = t & 63;
    const int w    = t >> 6;         // wave id = kg chunk = 16-row strip
    const int m0   = blockIdx.x * 64;
    const int e0   = blockIdx.y * 64;
    const int l15  = lane & 15, lq = lane >> 4;
    const bool isb0 = (blockIdx.x < 49);    // 3136/64: all rows in batch 0

    // A row geometry: m = b*3136 + d*196 + h*14 + w'; k = c*768 + kd*256 + kh*16 + kw
    int m = m0 + lane;
    int b = m / NTOK, n = m % NTOK;
    int d = n / 196, hw = n % 196;
    int h = hw / 14, ww = hw % 14;
    const float* vb = video + (size_t)b * 4816896 + (h * 16) * 224 + ww * 16;
    int dbase = 2 * d - 1;

    f32x4 acc[4] = {};
    for (int step = 0; step < 72; ++step) {
        int k0  = step * 32 + w * 8;     // wave-uniform
        int c   = k0 / 768;
        int rem = k0 - c * 768;
        int kd  = rem >> 8;
        int r2  = rem & 255;             // kh*16 + kw, (r2&15) in {0,8}
        int id  = dbase + kd;
        float4 a0 = make_float4(0.f, 0.f, 0.f, 0.f), a1 = a0;
        if (id >= 0) {
            const float* p = vb + (size_t)c * 1605632 + id * 50176 + (r2 >> 4) * 224 + (r2 & 15);
            a0 = *(const float4*)p;
            a1 = *(const float4*)(p + 4);
        }
        // B staging: async 16B/lane directly to LDS
        async16(cwh + (size_t)(e0 + lane) * KCV + k0, &Bh[w * 512]);
        if (isb0) async16(cwl + (size_t)(e0 + lane) * KCV + k0, &Bl[w * 512]);
        // A staging: hi (and lo for batch 0), one b128 write each
        float av[8] = {a0.x, a0.y, a0.z, a0.w, a1.x, a1.y, a1.z, a1.w};
        unsigned int ph[4];
        unsigned short hi[8];
#pragma unroll
        for (int j = 0; j < 4; ++j) {
            hi[2 * j]     = f2bf(av[2 * j]);
            hi[2 * j + 1] = f2bf(av[2 * j + 1]);
            ph[j] = (unsigned int)hi[2 * j] | ((unsigned int)hi[2 * j + 1] << 16);
        }
        *(uint4*)&Ah[w * 512 + lane * 8] = make_uint4(ph[0], ph[1], ph[2], ph[3]);
        if (isb0) {
            unsigned int pl[4];
#pragma unroll
            for (int j = 0; j < 4; ++j) {
                unsigned short q0 = f2bf(av[2 * j]     - bf2f(hi[2 * j]));
                unsigned short q1 = f2bf(av[2 * j + 1] - bf2f(hi[2 * j + 1]));
                pl[j] = (unsigned int)q0 | ((unsigned int)q1 << 16);
            }
            *(uint4*)&Al[w * 512 + lane * 8] = make_uint4(pl[0], pl[1], pl[2], pl[3]);
        }
        __syncthreads();
        // frags: A row = 16w + (l&15); k-chunk = l>>4
        short8 fah = *(const short8*)&Ah[(lq * 64 + w * 16 + l15) * 8];
        if (isb0) {
            short8 fal = *(const short8*)&Al[(lq * 64 + w * 16 + l15) * 8];
#pragma unroll
            for (int ct = 0; ct < 4; ++ct) {
                short8 fbh = *(const short8*)&Bh[(lq * 64 + ct * 16 + l15) * 8];
                short8 fbl = *(const short8*)&Bl[(lq * 64 + ct * 16 + l15) * 8];
                acc[ct] = __builtin_amdgcn_mfma_f32_16x16x32_bf16(fah, fbh, acc[ct], 0, 0, 0);
                acc[ct] = __builtin_amdgcn_mfma_f32_16x16x32_bf16(fah, fbl, acc[ct], 0, 0, 0);
                acc[ct] = __builtin_amdgcn_mfma_f32_16x16x32_bf16(fal, fbh, acc[ct], 0, 0, 0);
            }
        } else {
#pragma unroll
            for (int ct = 0; ct < 4; ++ct) {
                short8 fbh = *(const short8*)&Bh[(lq * 64 + ct * 16 + l15) * 8];
                acc[ct] = __builtin_amdgcn_mfma_f32_16x16x32_bf16(fah, fbh, acc[ct], 0, 0, 0);
            }
        }
        __syncthreads();
    }
    // C/D: col = lane&15, row = (lane>>4)*4 + reg  [m89]
    int rbase = m0 + w * 16 + lq * 4;
#pragma unroll
    for (int ct = 0; ct < 4; ++ct) {
        int e = e0 + ct * 16 + l15;
        float bias = cb[e];
#pragma unroll
        for (int r = 0; r < 4; ++r) {
            float v = fmaxf(acc[ct][r] + bias, 0.f);
            size_t off = (size_t)(rbase + r) * 256 + e;
            if (isb0) outF[off] = v;     // fp32 only needed for byte path (batch 0)
            outB[off] = f2bf(v);
        }
    }
}

// ---------- bf16 MFMA GEMM, K=256 staged fully in LDS (lean round-2 version) ----------
// C[m,e] = sum_k A[m,k]*W[e,k] + bias[e] (+addvec[e]) (mask m%NTOK >= *Sptr -> 0)
__global__ __launch_bounds__(256) void gemm_mfma_k(
    const unsigned short* __restrict__ A, const unsigned short* __restrict__ W,
    const float* __restrict__ bias, const float* __restrict__ addvec,
    const int* __restrict__ Sptr, float* __restrict__ outF, unsigned short* __restrict__ outB)
{
    __shared__ __align__(16) unsigned short As[16384], Bs[16384];   // 32 KB + 32 KB
    const int t = threadIdx.x, lane = t & 63, w = t >> 6;
    const int m0 = blockIdx.x * 64, e0 = blockIdx.y * 64;
    const int l15 = lane & 15, lq = lane >> 4;
    const unsigned short* ga = A + (size_t)(m0 + lane) * 256;
    const unsigned short* gb = W + (size_t)(e0 + lane) * 256;
#pragma unroll
    for (int kg = w; kg < 32; kg += 4) {
        async16(ga + kg * 8, &As[kg * 512]);
        async16(gb + kg * 8, &Bs[kg * 512]);
    }
    f32x4 acc[4] = {};
    __syncthreads();
#pragma unroll
    for (int s = 0; s < 8; ++s) {
        int kg = s * 4 + lq;
        short8 a = *(const short8*)&As[(kg * 64 + w * 16 + l15) * 8];
#pragma unroll
        for (int ct = 0; ct < 4; ++ct) {
            short8 bb = *(const short8*)&Bs[(kg * 64 + ct * 16 + l15) * 8];
            acc[ct] = __builtin_amdgcn_mfma_f32_16x16x32_bf16(a, bb, acc[ct], 0, 0, 0);
        }
    }
    int S = Sptr ? *Sptr : 0x7fffffff;
    int rbase = m0 + w * 16 + lq * 4;
#pragma unroll
    for (int ct = 0; ct < 4; ++ct) {
        int e = e0 + ct * 16 + l15;
        float bv = bias[e] + (addvec ? addvec[e] : 0.f);
#pragma unroll
        for (int r = 0; r < 4; ++r) {
            int mm = rbase + r;
            float v = acc[ct][r] + bv;
            if ((mm % NTOK) >= S) v = 0.f;
            size_t off = (size_t)mm * 256 + e;
            if (outF) outF[off] = v;
            if (outB) outB[off] = f2bf(v);
        }
    }
}

// ---------- scores-only GEMM clone: kp never materialized ----------
// scOut[(b*4+h)*NTOK+n] = sum_{e in head h=blockIdx.y} (kln@Wki.T + bki)[m,e] * qp[e]
__global__ __launch_bounds__(256) void gemm_sc_k(
    const unsigned short* __restrict__ A, const unsigned short* __restrict__ W,
    const float* __restrict__ bias, const float* __restrict__ qpv, float* __restrict__ scOut)
{
    __shared__ __align__(16) unsigned short As[16384], Bs[16384];
    const int t = threadIdx.x, lane = t & 63, w = t >> 6;
    const int m0 = blockIdx.x * 64, e0 = blockIdx.y * 64;
    const int l15 = lane & 15, lq = lane >> 4;
    const unsigned short* ga = A + (size_t)(m0 + lane) * 256;
    const unsigned short* gb = W + (size_t)(e0 + lane) * 256;
#pragma unroll
    for (int kg = w; kg < 32; kg += 4) {
        async16(ga + kg * 8, &As[kg * 512]);
        async16(gb + kg * 8, &Bs[kg * 512]);
    }
    f32x4 acc[4] = {};
    __syncthreads();
#pragma unroll
    for (int s = 0; s < 8; ++s) {
        int kg = s * 4 + lq;
        short8 a = *(const short8*)&As[(kg * 64 + w * 16 + l15) * 8];
#pragma unroll
        for (int ct = 0; ct < 4; ++ct) {
            short8 bb = *(const short8*)&Bs[(kg * 64 + ct * 16 + l15) * 8];
            acc[ct] = __builtin_amdgcn_mfma_f32_16x16x32_bf16(a, bb, acc[ct], 0, 0, 0);
        }
    }
    int rbase = m0 + w * 16 + lq * 4;
    float p[4] = {0.f, 0.f, 0.f, 0.f};
#pragma unroll
    for (int ct = 0; ct < 4; ++ct) {
        int e = e0 + ct * 16 + l15;
        float bv = bias[e];
        float qv = qpv[e];
#pragma unroll
        for (int r = 0; r < 4; ++r) p[r] += (acc[ct][r] + bv) * qv;
    }
#pragma unroll
    for (int r = 0; r < 4; ++r) {
        p[r] += __shfl_xor(p[r], 1); p[r] += __shfl_xor(p[r], 2);
        p[r] += __shfl_xor(p[r], 4); p[r] += __shfl_xor(p[r], 8);
    }
    if (l15 == 0) {
#pragma unroll
        for (int r = 0; r < 4; ++r) {
            int mm = rbase + r;
            int b = mm / NTOK, n = mm % NTOK;
            scOut[(b * 4 + blockIdx.y) * NTOK + n] = p[r];
        }
    }
}

// ---------- byte -> entropy -> boundary (b=0 only); one wave per token ----------
__global__ __launch_bounds__(256) void boundary_k(
    const float* __restrict__ tokens, const float* __restrict__ ent_table,
    int* __restrict__ boundary)
{
    int n    = blockIdx.x * 4 + (threadIdx.x >> 6);
    int lane = threadIdx.x & 63;
    const float4 x = reinterpret_cast<const float4*>(tokens + (size_t)n * 256)[lane];
    float mean = wsum(x.x + x.y + x.z + x.w) * (1.f / 256.f);
    float bf = rintf(mean * 255.f);
    bf = fminf(fmaxf(bf, 0.f), 255.f);
    int byte = (int)bf;
    const float4 lg = reinterpret_cast<const float4*>(ent_table + byte * 256)[lane];
    float mx = wmax(fmaxf(fmaxf(lg.x, lg.y), fmaxf(lg.z, lg.w)));
    float e0 = expf(lg.x - mx), e1 = expf(lg.y - mx), e2 = expf(lg.z - mx), e3 = expf(lg.w - mx);
    float z = wsum(e0 + e1 + e2 + e3);
    float iz = 1.f / z;
    float p0 = e0 * iz, p1 = e1 * iz, p2 = e2 * iz, p3 = e3 * iz;
    float ep = -(p0 * log2f(p0 + 1e-9f) + p1 * log2f(p1 + 1e-9f) +
                 p2 * log2f(p2 + 1e-9f) + p3 * log2f(p3 + 1e-9f));
    ep = wsum(ep);
    if (lane == 0) boundary[n] = (ep > THRESH) ? 1 : 0;
}

// ---------- single-block scan: boundary -> seg_start[], S ----------
__global__ __launch_bounds__(256) void scan_k(const int* __restrict__ boundary,
    int* __restrict__ seg_start, int* __restrict__ Sptr)
{
    __shared__ int sums[256];
    const int t = threadIdx.x;
    const int CH = 13;
    int base = t * CH;
    int s = 0;
    for (int i = 0; i < CH; i++) { int n = base + i; if (n < NTOK) s += boundary[n]; }
    sums[t] = s; __syncthreads();
    for (int o = 1; o < 256; o <<= 1) {
        int v = sums[t];
        int u = (t >= o) ? sums[t - o] : 0;
        __syncthreads();
        sums[t] = v + u;
        __syncthreads();
    }
    int run = (t == 0) ? 0 : sums[t - 1];
    if (t == 0) seg_start[0] = 0;
    for (int i = 0; i < CH; i++) {
        int n = base + i;
        if (n >= NTOK) break;
        int v = boundary[n];
        if (n == NTOK - 1) { Sptr[0] = run + 1; seg_start[run + 1] = NTOK; }
        if (v && (n + 1 < NTOK)) seg_start[run + 1] = n + 1;
        run += v;
    }
}

// ---------- row LayerNorm: fp32 in -> bf16 out; one wave per row ----------
__global__ __launch_bounds__(256) void ln_bf_k(const float* __restrict__ X,
    const float* __restrict__ g, const float* __restrict__ b, unsigned short* __restrict__ Y)
{
    int row  = blockIdx.x * 4 + (threadIdx.x >> 6);
    int lane = threadIdx.x & 63;
    float4 x = reinterpret_cast<const float4*>(X + (size_t)row * 256)[lane];
    float m = wsum(x.x + x.y + x.z + x.w) * (1.f / 256.f);
    float d0 = x.x - m, d1 = x.y - m, d2 = x.z - m, d3 = x.w - m;
    float var = wsum(d0 * d0 + d1 * d1 + d2 * d2 + d3 * d3) * (1.f / 256.f);
    float inv = 1.f / sqrtf(var + LN_EPS);
    float4 g4 = reinterpret_cast<const float4*>(g)[lane];
    float4 b4 = reinterpret_cast<const float4*>(b)[lane];
    ushort4 y;
    y.x = f2bf(d0 * inv * g4.x + b4.x);
    y.y = f2bf(d1 * inv * g4.y + b4.y);
    y.z = f2bf(d2 * inv * g4.z + b4.z);
    y.w = f2bf(d3 * inv * g4.w + b4.w);
    reinterpret_cast<ushort4*>(Y + (size_t)row * 256)[lane] = y;
}

// ---------- query path: qp[256], batch-invariant, one block, coalesced ----------
__global__ __launch_bounds__(256) void query_k(
    const float* __restrict__ gq, const float* __restrict__ wq_w, const float* __restrict__ wq_b,
    const float* __restrict__ lnq_g, const float* __restrict__ lnq_b,
    const float* __restrict__ inW, const float* __restrict__ inB, float* __restrict__ qp)
{
    __shared__ __align__(16) float sh[256];
    __shared__ float red[256];
    const int t = threadIdx.x, w = t >> 6, lane = t & 63;
    float4 g4 = reinterpret_cast<const float4*>(gq)[lane];
    for (int i = 0; i < 64; ++i) {
        int o = w * 64 + i;
        float4 wr = reinterpret_cast<const float4*>(wq_w + (size_t)o * 256)[lane];
        float pv = wsum(g4.x * wr.x + g4.y * wr.y + g4.z * wr.z + g4.w * wr.w);
        if (lane == 0) sh[o] = pv + wq_b[o];
    }
    __syncthreads();
    float acc = sh[t];
    red[t] = acc; __syncthreads();
    for (int o = 128; o > 0; o >>= 1) { if (t < o) red[t] += red[t + o]; __syncthreads(); }
    float m = red[0] * (1.f / 256.f);
    __syncthreads();
    float d = acc - m;
    red[t] = d * d; __syncthreads();
    for (int o = 128; o > 0; o >>= 1) { if (t < o) red[t] += red[t + o]; __syncthreads(); }
    float inv = 1.f / sqrtf(red[0] * (1.f / 256.f) + LN_EPS);
    __syncthreads();
    sh[t] = d * inv * lnq_g[t] + lnq_b[t];
    __syncthreads();
    float4 s4 = reinterpret_cast<const float4*>(sh)[lane];
    for (int i = 0; i < 64; ++i) {
        int o = w * 64 + i;
        float4 wr = reinterpret_cast<const float4*>(inW + (size_t)o * 256)[lane];
        float pv = wsum(s4.x * wr.x + s4.y * wr.y + s4.z * wr.z + s4.w * wr.w);
        if (lane == 0) qp[o] = (pv + inB[o]) * 0.125f;
    }
}

// ---------- segment softmax-attention; grid (NTOK, NH); wave = batch ----------
__global__ __launch_bounds__(256) void attn_bf_k(const float* __restrict__ sc,
    const unsigned short* __restrict__ vp, const int* __restrict__ seg_start,
    const int* __restrict__ Sptr, unsigned short* __restrict__ attn)
{
    int s    = blockIdx.x;
    int h    = blockIdx.y;
    int b    = threadIdx.x >> 6;
    int lane = threadIdx.x & 63;
    unsigned short* orow = attn + ((size_t)b * NTOK + s) * 256 + h * 64;
    int S = *Sptr;
    if (s >= S) { orow[lane] = 0; return; }
    int st = seg_start[s], en = seg_start[s + 1];
    const float* scr = sc + (b * 4 + h) * NTOK;
    float m = -1e30f;
    for (int n = st; n < en; n++) m = fmaxf(m, scr[n]);
    float den = 0.f, acc = 0.f;
    for (int n = st; n < en; n++) {
        float wgt = expf(scr[n] - m);
        den += wgt;
        acc += wgt * bf2f(vp[((size_t)b * NTOK + n) * 256 + h * 64 + lane]);
    }
    orow[lane] = f2bf(acc / den);
}

extern "C" void kernel_launch(void* const* d_in, const int* in_sizes, int n_in,
                              void* d_out, int out_size, void* d_ws, size_t ws_size,
                              hipStream_t stream)
{
    const float* video      = (const float*)d_in[0];
    const float* conv_w     = (const float*)d_in[1];
    const float* conv_b     = (const float*)d_in[2];
    const float* wq_w       = (const float*)d_in[3];
    const float* wq_b       = (const float*)d_in[4];
    const float* wk_w       = (const float*)d_in[5];
    const float* wk_b       = (const float*)d_in[6];
    const float* wv_w       = (const float*)d_in[7];
    const float* wv_b       = (const float*)d_in[8];
    const float* lnq_g      = (const float*)d_in[9];
    const float* lnq_b      = (const float*)d_in[10];
    const float* lnk_g      = (const float*)d_in[11];
    const float* lnk_b      = (const float*)d_in[12];
    const float* lnv_g      = (const float*)d_in[13];
    const float* lnv_b      = (const float*)d_in[14];
    const float* in_proj_w  = (const float*)d_in[15];
    const float* in_proj_b  = (const float*)d_in[16];
    const float* out_proj_w = (const float*)d_in[17];
    const float* out_proj_b = (const float*)d_in[18];
    const float* dense_w    = (const float*)d_in[19];
    const float* dense_b    = (const float*)d_in[20];
    const float* bproj_w    = (const float*)d_in[21];
    const float* bproj_b    = (const float*)d_in[22];
    const float* group_q    = (const float*)d_in[23];
    const float* ent_table  = (const float*)d_in[24];
    float* out = (float*)d_out;

    // ---- workspace layout ----
    float* W1f = (float*)d_ws;                         // fp32 tokens (batch 0 only used)
    float* P   = W1f + (size_t)MT * 256;               // fp32 pre-LN buffer
    unsigned short* B1 = (unsigned short*)(P + (size_t)MT * 256);  // tokens_b16 / attn_b16
    unsigned short* B2 = B1 + (size_t)MT * 256;        // kln/vln/o1
    unsigned short* B3 = B2 + (size_t)MT * 256;        // vp/o2
    unsigned short* cwh = B3 + (size_t)MT * 256;       // conv weights hi
    unsigned short* cwl = cwh + 256 * KCV;             // conv weights lo
    unsigned short* wpool = cwl + 256 * KCV;           // 524288 bf16 weights
    float* sc = (float*)(wpool + 524288);              // scores [B*NH][NTOK]
    float* qp = sc + 16 * NTOK;
    int* boundary  = (int*)(qp + 256);
    int* seg_start = boundary + NTOK;
    int* Sp        = seg_start + (NTOK + 1);

    const unsigned short* wkb    = wpool;
    const unsigned short* wvb    = wpool + 65536;
    const unsigned short* inpb   = wpool + 131072;     // 3E x E
    const unsigned short* outpb  = wpool + 327680;
    const unsigned short* denseb = wpool + 393216;
    const unsigned short* bprojb = wpool + 458752;

    dim3 gG(196, 4), blk(256);
    prep_k<<<dim3(4352), blk, 0, stream>>>(conv_w, cwh, cwl, wk_w, wv_w, in_proj_w,
                                           out_proj_w, dense_w, bproj_w, wpool);
    conv_mfma2_k<<<gG, blk, 0, stream>>>(video, cwh, cwl, conv_b, W1f, B1);
    boundary_k<<<dim3(NTOK / 4), blk, 0, stream>>>(W1f, ent_table, boundary);
    scan_k<<<dim3(1), blk, 0, stream>>>(boundary, seg_start, Sp);
    query_k<<<dim3(1), blk, 0, stream>>>(group_q, wq_w, wq_b, lnq_g, lnq_b,
                                         in_proj_w, in_proj_b, qp);
    // K path (scores fused into kp GEMM epilogue; kp never materialized)
    gemm_mfma_k<<<gG, blk, 0, stream>>>(B1, wkb, wk_b, nullptr, nullptr, P, nullptr);
    ln_bf_k<<<dim3(MT / 4), blk, 0, stream>>>(P, lnk_g, lnk_b, B2);
    gemm_sc_k<<<gG, blk, 0, stream>>>(B2, inpb + 65536, in_proj_b + 256, qp, sc);
    // V path
    gemm_mfma_k<<<gG, blk, 0, stream>>>(B1, wvb, wv_b, nullptr, nullptr, P, nullptr);
    ln_bf_k<<<dim3(MT / 4), blk, 0, stream>>>(P, lnv_g, lnv_b, B2);
    gemm_mfma_k<<<gG, blk, 0, stream>>>(B2, inpb + 131072, in_proj_b + 512,
                                        nullptr, nullptr, nullptr, B3);   // vp
    // segment attention
    attn_bf_k<<<dim3(NTOK, 4), blk, 0, stream>>>(sc, B3, seg_start, Sp, B1);
    // tail projections
    gemm_mfma_k<<<gG, blk, 0, stream>>>(B1, outpb, out_proj_b, nullptr, nullptr,
                                        nullptr, B2);
    gemm_mfma_k<<<gG, blk, 0, stream>>>(B2, denseb, dense_b, group_q, nullptr,
                                        nullptr, B3);
    gemm_mfma_k<<<gG, blk, 0, stream>>>(B3, bprojb, bproj_b, nullptr, Sp,
                                        out, nullptr);
}